// Round 4
// baseline (161.950 us; speedup 1.0000x reference)
//
#include <hip/hip_runtime.h>
#include <hip/hip_bf16.h>

#define BB  8
#define CC  128
#define LXX 4096
#define LYY 1024
#define HH  4
#define DHH 32

typedef __attribute__((ext_vector_type(8))) short bf16x8;
typedef __attribute__((ext_vector_type(4))) float f32x4;

static __device__ __forceinline__ unsigned short f2bf(float f) {
    __hip_bfloat16 h = __float2bfloat16(f);
    return *reinterpret_cast<unsigned short*>(&h);
}

static __device__ __forceinline__ bf16x8 pack8(const float* f) {
    bf16x8 r;
#pragma unroll
    for (int i = 0; i < 8; ++i) {
        __hip_bfloat16 h = __float2bfloat16(f[i]);
        r[i] = *reinterpret_cast<short*>(&h);
    }
    return r;
}

// ================= merged MFMA projection (+fused conv for x) — unchanged from R3 =================
__global__ __launch_bounds__(256) void proj_all_kernel(
    const float* __restrict__ x, const float* __restrict__ y,
    const float* __restrict__ ipw, const float* __restrict__ ipb,
    const float* __restrict__ c1w, const float* __restrict__ c1b,
    const float* __restrict__ c2w, const float* __restrict__ c2b,
    unsigned short* __restrict__ Qb, unsigned short* __restrict__ Kb,
    float* __restrict__ localS, float qscale)
{
    int tid  = threadIdx.x;
    int wv   = tid >> 6;
    int lane = tid & 63;
    int n16  = lane & 15;
    int quad = lane >> 4;

    int blk = blockIdx.x;
    bool isX = (blk < 512);
    const float* src; const float* wrow; const float* bias;
    unsigned short* dst; int L, bi, l0; float scale;
    if (isX) {
        bi = blk >> 6; l0 = (blk & 63) * 64;
        src = x + (size_t)bi * CC * LXX; L = LXX;
        wrow = ipw; bias = ipb; dst = Qb; scale = qscale;
    } else {
        int b2 = blk - 512;
        bi = b2 >> 4; l0 = (b2 & 15) * 64;
        src = y + (size_t)bi * CC * LYY; L = LYY;
        wrow = ipw + CC * CC; bias = ipb + CC; dst = Kb; scale = 1.0f;
    }
    int lw = l0 + wv * 16;
    int myl = lw + n16;

    bf16x8 bfr[4];
#pragma unroll
    for (int kk = 0; kk < 4; ++kk) {
        float t[8];
        const float* p = src + (size_t)(kk * 32 + quad * 8) * L + myl;
#pragma unroll
        for (int j = 0; j < 8; ++j) t[j] = p[(size_t)j * L];
        bfr[kk] = pack8(t);
    }

    const f32x4 fzero = {0.f, 0.f, 0.f, 0.f};

#pragma unroll 1
    for (int m = 0; m < 8; ++m) {
        int mc = m * 16;
        f32x4 acc = fzero;
#pragma unroll
        for (int kk = 0; kk < 4; ++kk) {
            const float* wp = wrow + (size_t)(mc + n16) * CC + kk * 32 + quad * 8;
            float t[8];
            *(float4*)(t) = *(const float4*)(wp);
            *(float4*)(t + 4) = *(const float4*)(wp + 4);
            bf16x8 afr = pack8(t);
            acc = __builtin_amdgcn_mfma_f32_16x16x32_bf16(afr, bfr[kk], acc, 0, 0, 0);
        }
        int h = mc >> 5, d0 = (mc & 31) + quad * 4;
        ushort4 u;
        float4 bq = *(const float4*)(bias + mc + quad * 4);
        u.x = f2bf((acc[0] + bq.x) * scale);
        u.y = f2bf((acc[1] + bq.y) * scale);
        u.z = f2bf((acc[2] + bq.z) * scale);
        u.w = f2bf((acc[3] + bq.w) * scale);
        *(ushort4*)(dst + (((size_t)(bi * HH + h) * L) + myl) * DHH + d0) = u;
    }

    if (isX) {
        float p = 0.f;
#pragma unroll
        for (int m2 = 0; m2 < 2; ++m2) {
            f32x4 hacc = fzero;
#pragma unroll
            for (int kk = 0; kk < 4; ++kk) {
                const float* wp = c1w + (size_t)(m2 * 16 + n16) * CC + kk * 32 + quad * 8;
                float t[8];
                *(float4*)(t) = *(const float4*)(wp);
                *(float4*)(t + 4) = *(const float4*)(wp + 4);
                bf16x8 afr = pack8(t);
                hacc = __builtin_amdgcn_mfma_f32_16x16x32_bf16(afr, bfr[kk], hacc, 0, 0, 0);
            }
#pragma unroll
            for (int r = 0; r < 4; ++r) {
                int o = m2 * 16 + quad * 4 + r;
                p = fmaf(c2w[o], fmaxf(hacc[r] + c1b[o], 0.0f), p);
            }
        }
        p += __shfl_xor(p, 16, 64);
        p += __shfl_xor(p, 32, 64);
        if (quad == 0) {
            float s = p + c2b[0];
            localS[(size_t)bi * LXX + myl] = 1.0f / (1.0f + __expf(-s));
        }
    }
}

// ================= fused attention v3: 8 waves/block, 128 keys/wave =================
// block = 512 thr (8 waves): 16 q rows, wave w owns keys [w*128, +128) = 8 t-tiles.
// Per-wave state: s[8] + vAcc[8] = 64 acc regs (vs 128 in v2) -> ~120 total -> 4 waves/EU.
__global__ __launch_bounds__(512, 4) void attn_kernel(
    const unsigned short* __restrict__ Qh, const unsigned short* __restrict__ Kh,
    const float* __restrict__ localS,
    const float* __restrict__ gw, const float* __restrict__ gb,
    float* __restrict__ out)
{
    int tid = threadIdx.x;
    int wave = tid >> 6;        // 0..7
    int lane = tid & 63;
    int n16 = lane & 15;
    int quad = lane >> 4;
    int bi = blockIdx.y;
    int q0 = blockIdx.x * 16;
    int row = quad * 4;

    __shared__ float lbuf[HH][8][16];
    __shared__ float mbuf[8][16];

    const unsigned short* Qp = Qh + (((size_t)bi * HH) * LXX + q0 + n16) * DHH + quad * 8;
    const unsigned short* Kp = Kh + (((size_t)bi * HH) * LYY + wave * 128 + n16) * DHH + quad * 8;

    const f32x4 fzero = {0.f, 0.f, 0.f, 0.f};
    f32x4 vAcc[8];
#pragma unroll
    for (int t = 0; t < 8; ++t) vAcc[t] = fzero;

#pragma unroll 1
    for (int h = 0; h < HH; ++h) {
        bf16x8 afr = *(const bf16x8*)(Qp + (size_t)h * LXX * DHH);
        const unsigned short* Kph = Kp + (size_t)h * LYY * DHH;
        f32x4 s[8];
#pragma unroll
        for (int t = 0; t < 8; ++t) {
            bf16x8 bfr = *(const bf16x8*)(Kph + (size_t)t * 16 * DHH);
            s[t] = __builtin_amdgcn_mfma_f32_16x16x32_bf16(afr, bfr, fzero, 0, 0, 0);
        }
        // exp2 (log2e folded into Q scale) + per-row partial sum; no max pass (safe: |s|<<120)
        float lr[4] = {0.f, 0.f, 0.f, 0.f};
#pragma unroll
        for (int t = 0; t < 8; ++t)
#pragma unroll
            for (int r = 0; r < 4; ++r) {
                float e = __builtin_amdgcn_exp2f(s[t][r]);
                s[t][r] = e;
                lr[r] += e;
            }
        // reduce across the 16 key-lanes of this quad
#pragma unroll
        for (int off = 1; off < 16; off <<= 1)
#pragma unroll
            for (int r = 0; r < 4; ++r) lr[r] += __shfl_xor(lr[r], off, 64);
        if (n16 == 0) {
#pragma unroll
            for (int r = 0; r < 4; ++r) lbuf[h][wave][row + r] = lr[r];
        }
        __syncthreads();
#pragma unroll
        for (int r = 0; r < 4; ++r) {
            float d = 0.f;
#pragma unroll
            for (int w = 0; w < 8; ++w) d += lbuf[h][w][row + r];
            float inv = 1.0f / d;
#pragma unroll
            for (int t = 0; t < 8; ++t) vAcc[t][r] += s[t][r] * inv;
        }
        // next head writes lbuf[h+1] (disjoint slots) -> no extra barrier
    }
    // max over this wave's 128 keys of the head-sum
    float vm[4] = {-1e30f, -1e30f, -1e30f, -1e30f};
#pragma unroll
    for (int t = 0; t < 8; ++t)
#pragma unroll
        for (int r = 0; r < 4; ++r) vm[r] = fmaxf(vm[r], vAcc[t][r]);
#pragma unroll
    for (int off = 1; off < 16; off <<= 1)
#pragma unroll
        for (int r = 0; r < 4; ++r) vm[r] = fmaxf(vm[r], __shfl_xor(vm[r], off, 64));
    if (n16 == 0) {
#pragma unroll
        for (int r = 0; r < 4; ++r) mbuf[wave][row + r] = vm[r];
    }
    __syncthreads();
    if (tid < 16) {
        float m = mbuf[0][tid];
#pragma unroll
        for (int w = 1; w < 8; ++w) m = fmaxf(m, mbuf[w][tid]);
        float cs = 0.25f * m;
        float ls = localS[(size_t)bi * LXX + q0 + tid];
        float z = gw[0] * cs + gw[1] * ls + gb[0];
        float alpha = 1.0f / (1.0f + __expf(-z));
        out[(size_t)bi * LXX + q0 + tid] = alpha * cs + (1.0f - alpha) * ls;
    }
}

extern "C" void kernel_launch(void* const* d_in, const int* in_sizes, int n_in,
                              void* d_out, int out_size, void* d_ws, size_t ws_size,
                              hipStream_t stream) {
    const float* x   = (const float*)d_in[0];
    const float* y   = (const float*)d_in[1];
    const float* ipw = (const float*)d_in[2];
    const float* ipb = (const float*)d_in[3];
    const float* c1w = (const float*)d_in[4];
    const float* c1b = (const float*)d_in[5];
    const float* c2w = (const float*)d_in[6];
    const float* c2b = (const float*)d_in[7];
    const float* gw  = (const float*)d_in[8];
    const float* gb  = (const float*)d_in[9];
    float* out = (float*)d_out;

    float* localS = (float*)d_ws;                                // 32768 f32
    unsigned short* Qb = (unsigned short*)(localS + 32768);      // B*H*LX*DH bf16
    unsigned short* Kb = Qb + (size_t)BB * HH * LXX * DHH;       // B*H*LY*DH bf16

    // 1/sqrt(32) * log2(e): exp2-domain softmax, folded into Q only
    const float qscale = 0.17677669529663687f * 1.4426950408889634f;

    hipLaunchKernelGGL(proj_all_kernel, dim3(640), dim3(256), 0, stream,
                       x, y, ipw, ipb, c1w, c1b, c2w, c2b, Qb, Kb, localS, qscale);
    hipLaunchKernelGGL(attn_kernel, dim3(LXX / 16, BB), dim3(512), 0, stream,
                       Qb, Kb, localS, gw, gb, out);
}